// Round 1
// baseline (105289.465 us; speedup 1.0000x reference)
//
#include <hip/hip_runtime.h>

typedef _Float16 f16;
typedef _Float16 f16x2 __attribute__((ext_vector_type(2)));
typedef _Float16 f16x4 __attribute__((ext_vector_type(4)));
typedef _Float16 f16x8 __attribute__((ext_vector_type(8)));
typedef float f32x4 __attribute__((ext_vector_type(4)));

#define HD 512
#define T_TOT 16384
#define RING 128
#define NWG 32

// ---------------- ws layout (bytes) ----------------
static const size_t O_XC    = 0;                       // 16384*2048 f16  = 64MB
static const size_t O_W1    = 67108864;                // 2048*2048 f16   = 8MB
static const size_t O_WHH   = 75497472;                // 2048*512 f16    = 2MB
static const size_t O_W2    = 77594624;                // 2048*512 f16    = 2MB
static const size_t O_G     = 79691776;                // 16384*2048 f32  = 128MB
static const size_t O_RING  = 213909504;               // 128*512 f16     = 128KB
static const size_t O_FLAGS = 214040576;               // 32 int

__device__ __forceinline__ float dot2f(f16x2 a, f16x2 b, float c) {
#if __has_builtin(__builtin_amdgcn_fdot2)
    return __builtin_amdgcn_fdot2(a, b, c, false);
#else
    return fmaf((float)a[0], (float)b[0], fmaf((float)a[1], (float)b[1], c));
#endif
}

__device__ __forceinline__ float sigf(float x) {
    return 1.0f / (1.0f + __expf(-x));
}
__device__ __forceinline__ float tanhfast(float x) {
    // tanh(x) = 1 - 2/(exp(2x)+1); saturates correctly for |x| large
    return 1.0f - 2.0f / (__expf(2.0f * x) + 1.0f);
}

// ---------- convert x,hi -> XC f16 [t=s*64+b][k 0..2048) ----------
__global__ __launch_bounds__(256) void conv_xc(const float* __restrict__ x,
                                               const float* __restrict__ hi,
                                               f16* __restrict__ xc) {
    int gid = blockIdx.x * 256 + threadIdx.x;      // 8,388,608 threads
    int t = gid >> 9;
    int k = (gid & 511) << 2;
    int b = t & 63, s = t >> 6;
    const float* src = (k < 1024) ? (x  + ((size_t)((b << 8) + s) << 10) + k)
                                  : (hi + ((size_t)((b << 8) + s) << 10) + (k - 1024));
    float4 v = *reinterpret_cast<const float4*>(src);
    f16x4 o = { (_Float16)v.x, (_Float16)v.y, (_Float16)v.z, (_Float16)v.w };
    *reinterpret_cast<f16x4*>(xc + ((size_t)t << 11) + k) = o;
}

// ---------- convert W_ih[:, :2048] -> W1 f16 row-major [j][k] ----------
__global__ __launch_bounds__(256) void conv_w1(const float* __restrict__ wih,
                                               f16* __restrict__ w1) {
    int gid = blockIdx.x * 256 + threadIdx.x;      // 2048*512 threads
    int j = gid >> 9;
    int k = (gid & 511) << 2;
    float4 v = *reinterpret_cast<const float4*>(wih + (size_t)j * 2560 + k);
    f16x4 o = { (_Float16)v.x, (_Float16)v.y, (_Float16)v.z, (_Float16)v.w };
    *reinterpret_cast<f16x4*>(w1 + ((size_t)j << 11) + k) = o;
}

// ---------- convert W_hh and W_ih[:, 2048:2560] -> f16 [j][k 0..512) ----------
__global__ __launch_bounds__(256) void conv_wc(const float* __restrict__ whh,
                                               const float* __restrict__ wih,
                                               f16* __restrict__ whhf,
                                               f16* __restrict__ w2f) {
    int gid = blockIdx.x * 256 + threadIdx.x;      // 2048*128 threads
    int j = gid >> 7;
    int k = (gid & 127) << 2;
    float4 a = *reinterpret_cast<const float4*>(whh + (size_t)j * 512 + k);
    f16x4 oa = { (_Float16)a.x, (_Float16)a.y, (_Float16)a.z, (_Float16)a.w };
    *reinterpret_cast<f16x4*>(whhf + ((size_t)j << 9) + k) = oa;
    float4 bv = *reinterpret_cast<const float4*>(wih + (size_t)j * 2560 + 2048 + k);
    f16x4 ob = { (_Float16)bv.x, (_Float16)bv.y, (_Float16)bv.z, (_Float16)bv.w };
    *reinterpret_cast<f16x4*>(w2f + ((size_t)j << 9) + k) = ob;
}

// ---------- G = XC @ W1^T + (b_ih+b_hh), f16 MFMA, fp32 out ----------
// grid (16,128), block 256.  Wave w: 64x64 tile; 4x4 fragments of 16x16x32.
__global__ __launch_bounds__(256) void gemm_pre(const f16* __restrict__ XC,
                                                const f16* __restrict__ W1,
                                                const float* __restrict__ b_ih,
                                                const float* __restrict__ b_hh,
                                                float* __restrict__ G) {
    int w = threadIdx.x >> 6, l = threadIdx.x & 63;
    int R0 = blockIdx.y * 128 + (w >> 1) * 64;
    int C0 = blockIdx.x * 128 + (w & 1) * 64;
    int lr = l & 15, kb = l >> 4;                      // kb: 0..3
    f32x4 acc[4][4] = {};
    const f16* Abase = XC + (size_t)(R0 + lr) * 2048 + kb * 8;
    const f16* Bbase = W1 + (size_t)(C0 + lr) * 2048 + kb * 8;
    for (int kk = 0; kk < 2048; kk += 32) {
        f16x8 av[4], bv[4];
#pragma unroll
        for (int i = 0; i < 4; i++)
            av[i] = *reinterpret_cast<const f16x8*>(Abase + (size_t)(i * 16) * 2048 + kk);
#pragma unroll
        for (int i = 0; i < 4; i++)
            bv[i] = *reinterpret_cast<const f16x8*>(Bbase + (size_t)(i * 16) * 2048 + kk);
#pragma unroll
        for (int fr = 0; fr < 4; fr++)
#pragma unroll
            for (int fc = 0; fc < 4; fc++)
                acc[fr][fc] = __builtin_amdgcn_mfma_f32_16x16x32_f16(av[fr], bv[fc], acc[fr][fc], 0, 0, 0);
    }
#pragma unroll
    for (int fc = 0; fc < 4; fc++) {
        int col = C0 + fc * 16 + lr;
        float bias = b_ih[col] + b_hh[col];
#pragma unroll
        for (int fr = 0; fr < 4; fr++) {
#pragma unroll
            for (int r = 0; r < 4; r++) {
                int row = R0 + fr * 16 + kb * 4 + r;
                G[(size_t)row * 2048 + col] = acc[fr][fc][r] + bias;
            }
        }
    }
}

// ---------- the sequential chain: 32 persistent WGs, weights in registers ----------
// WG wg owns hidden units [wg*16, wg*16+16).  256 threads:
//   wave w = gate (i,f,g,o); lane l: u=l&15 unit, m=(l>>4)&1 matrix (0=Whh,1=W2), hf=l>>5 k-half.
// Each thread: 256-MAC half-dot, weights preloaded into 128 packed-f16 VGPRs.
__global__ __launch_bounds__(256, 1) void lstm_chain(const float* __restrict__ G,
                                                     const f16* __restrict__ Whhf,
                                                     const f16* __restrict__ W2f,
                                                     f16* __restrict__ h_ring,
                                                     int* __restrict__ flags,
                                                     float* __restrict__ out) {
    const int wg = blockIdx.x;
    const int tid = threadIdx.x;
    const int w = tid >> 6, l = tid & 63;
    const int m = (l >> 4) & 1, hf = l >> 5, u = l & 15;
    const int row = w * 512 + wg * 16 + u;

    const f16* Wsrc = (m ? W2f : Whhf) + (size_t)row * 512 + hf * 256;
    f16x2 wreg[128];
#pragma unroll
    for (int i = 0; i < 32; i++) {
        f16x8 v = reinterpret_cast<const f16x8*>(Wsrc)[i];
        wreg[4 * i + 0] = v.lo.lo;
        wreg[4 * i + 1] = v.lo.hi;
        wreg[4 * i + 2] = v.hi.lo;
        wreg[4 * i + 3] = v.hi.hi;
    }

    __shared__ float gate_lds[4][16];
    float cstate = 0.0f;

    for (int t = 0; t < T_TOT; t++) {
        // G_pre (includes bias) — independent load, issue early
        float gval = 0.0f;
        if (l < 16) gval = G[(size_t)t * 2048 + w * 512 + wg * 16 + l];

        float acc = 0.0f;
        // W2 · h[t-64]: 64 steps of slack — no barrier needed (synced via earlier acquires)
        if (m == 1 && t >= 64) {
            const f16* hp = h_ring + ((t - 64) & (RING - 1)) * HD + hf * 256;
#pragma unroll
            for (int i = 0; i < 32; i++) {
                f16x8 hv = reinterpret_cast<const f16x8*>(hp)[i];
                acc = dot2f(wreg[4 * i + 0], hv.lo.lo, acc);
                acc = dot2f(wreg[4 * i + 1], hv.lo.hi, acc);
                acc = dot2f(wreg[4 * i + 2], hv.hi.lo, acc);
                acc = dot2f(wreg[4 * i + 3], hv.hi.hi, acc);
            }
        }

        // barrier: wait until every WG finished step t-1 (flags[w] >= t)
        if (t > 0) {
            bool ok;
            do {
                int f = 0x7fffffff;
                if (l < NWG)
                    f = __hip_atomic_load(&flags[l], __ATOMIC_ACQUIRE, __HIP_MEMORY_SCOPE_AGENT);
                ok = __all(f >= t);
            } while (!ok);
        }

        // W_hh · h[t-1]  (t=0 reads zeroed slot 127)
        if (m == 0) {
            const f16* hp = h_ring + ((t - 1) & (RING - 1)) * HD + hf * 256;
#pragma unroll
            for (int i = 0; i < 32; i++) {
                f16x8 hv = reinterpret_cast<const f16x8*>(hp)[i];
                acc = dot2f(wreg[4 * i + 0], hv.lo.lo, acc);
                acc = dot2f(wreg[4 * i + 1], hv.lo.hi, acc);
                acc = dot2f(wreg[4 * i + 2], hv.hi.lo, acc);
                acc = dot2f(wreg[4 * i + 3], hv.hi.hi, acc);
            }
        }

        // reduce: hf halves (xor 32), then matrices (xor 16)
        acc += __shfl_xor(acc, 32);
        acc += __shfl_xor(acc, 16);
        if (l < 16) gate_lds[w][l] = acc + gval;
        __syncthreads();

        if (tid < 16) {
            float gi = gate_lds[0][tid];
            float gf = gate_lds[1][tid];
            float gg = gate_lds[2][tid];
            float go = gate_lds[3][tid];
            cstate = sigf(gf) * cstate + sigf(gi) * tanhfast(gg);
            float h = sigf(go) * tanhfast(cstate);
            int b = t & 63, s = t >> 6;
            out[(((size_t)(b << 8) + s) << 9) + wg * 16 + tid] = h;
            h_ring[(t & (RING - 1)) * HD + wg * 16 + tid] = (_Float16)h;
        }
        __syncthreads();
        if (tid == 0)
            __hip_atomic_store(&flags[wg], t + 1, __ATOMIC_RELEASE, __HIP_MEMORY_SCOPE_AGENT);
    }
}

extern "C" void kernel_launch(void* const* d_in, const int* in_sizes, int n_in,
                              void* d_out, int out_size, void* d_ws, size_t ws_size,
                              hipStream_t stream) {
    const float* x    = (const float*)d_in[0];
    const float* hi   = (const float*)d_in[1];
    const float* W_ih = (const float*)d_in[2];
    const float* W_hh = (const float*)d_in[3];
    const float* b_ih = (const float*)d_in[4];
    const float* b_hh = (const float*)d_in[5];

    char* ws = (char*)d_ws;
    f16*   XCf   = (f16*)(ws + O_XC);
    f16*   W1f   = (f16*)(ws + O_W1);
    f16*   Whhf  = (f16*)(ws + O_WHH);
    f16*   W2f   = (f16*)(ws + O_W2);
    float* G     = (float*)(ws + O_G);
    f16*   hring = (f16*)(ws + O_RING);
    int*   flags = (int*)(ws + O_FLAGS);

    // zero h_ring (slot 127 = h[-1]=0) and the flags, every launch (ws not re-poisoned)
    hipMemsetAsync(hring, 0, (RING * HD * sizeof(f16)) + 128, stream);

    conv_xc<<<32768, 256, 0, stream>>>(x, hi, XCf);
    conv_w1<<<4096, 256, 0, stream>>>(W_ih, W1f);
    conv_wc<<<1024, 256, 0, stream>>>(W_hh, W_ih, Whhf, W2f);
    gemm_pre<<<dim3(16, 128), 256, 0, stream>>>(XCf, W1f, b_ih, b_hh, G);
    lstm_chain<<<NWG, 256, 0, stream>>>(G, Whhf, W2f, hring, flags, (float*)d_out);
}

// Round 2
// 59423.444 us; speedup vs baseline: 1.7719x; 1.7719x over previous
//
#include <hip/hip_runtime.h>

typedef _Float16 f16;
typedef _Float16 f16x2 __attribute__((ext_vector_type(2)));
typedef _Float16 f16x4 __attribute__((ext_vector_type(4)));
typedef _Float16 f16x8 __attribute__((ext_vector_type(8)));
typedef float f32x4 __attribute__((ext_vector_type(4)));
typedef unsigned long long ull;

#define HD 512
#define T_TOT 16384
#define RING 128
#define NWG 32

// ---------------- ws layout (bytes) ----------------
static const size_t O_XC    = 0;                       // 16384*2048 f16  = 64MB
static const size_t O_W1    = 67108864;                // 2048*2048 f16   = 8MB
static const size_t O_WHH   = 75497472;                // 2048*512 f16    = 2MB
static const size_t O_W2    = 77594624;                // 2048*512 f16    = 2MB
static const size_t O_G     = 79691776;                // 16384*2048 f32  = 128MB
static const size_t O_RING  = 213909504;               // 128*512 f16     = 128KB
static const size_t O_FLAGS = 214040576;               // 32 int

__device__ __forceinline__ float dot2f(f16x2 a, f16x2 b, float c) {
#if __has_builtin(__builtin_amdgcn_fdot2)
    return __builtin_amdgcn_fdot2(a, b, c, false);
#else
    return fmaf((float)a[0], (float)b[0], fmaf((float)a[1], (float)b[1], c));
#endif
}

__device__ __forceinline__ float sigf(float x) {
    return 1.0f / (1.0f + __expf(-x));
}
__device__ __forceinline__ float tanhfast(float x) {
    return 1.0f - 2.0f / (__expf(2.0f * x) + 1.0f);
}

// relaxed agent-scope helpers (sc0 sc1 -> coherent at L3, no inv/wb fences)
__device__ __forceinline__ ull ld_a64(const ull* p) {
    return __hip_atomic_load((const ull*)p, __ATOMIC_RELAXED, __HIP_MEMORY_SCOPE_AGENT);
}
__device__ __forceinline__ int ld_a32(const int* p) {
    return __hip_atomic_load((const int*)p, __ATOMIC_RELAXED, __HIP_MEMORY_SCOPE_AGENT);
}
__device__ __forceinline__ void st_a64(ull* p, ull v) {
    __hip_atomic_store(p, v, __ATOMIC_RELAXED, __HIP_MEMORY_SCOPE_AGENT);
}
__device__ __forceinline__ void st_a32(int* p, int v) {
    __hip_atomic_store(p, v, __ATOMIC_RELAXED, __HIP_MEMORY_SCOPE_AGENT);
}

// ---------- convert x,hi -> XC f16 [t=s*64+b][k 0..2048) ----------
__global__ __launch_bounds__(256) void conv_xc(const float* __restrict__ x,
                                               const float* __restrict__ hi,
                                               f16* __restrict__ xc) {
    int gid = blockIdx.x * 256 + threadIdx.x;
    int t = gid >> 9;
    int k = (gid & 511) << 2;
    int b = t & 63, s = t >> 6;
    const float* src = (k < 1024) ? (x  + ((size_t)((b << 8) + s) << 10) + k)
                                  : (hi + ((size_t)((b << 8) + s) << 10) + (k - 1024));
    float4 v = *reinterpret_cast<const float4*>(src);
    f16x4 o = { (_Float16)v.x, (_Float16)v.y, (_Float16)v.z, (_Float16)v.w };
    *reinterpret_cast<f16x4*>(xc + ((size_t)t << 11) + k) = o;
}

// ---------- convert W_ih[:, :2048] -> W1 f16 row-major [j][k] ----------
__global__ __launch_bounds__(256) void conv_w1(const float* __restrict__ wih,
                                               f16* __restrict__ w1) {
    int gid = blockIdx.x * 256 + threadIdx.x;
    int j = gid >> 9;
    int k = (gid & 511) << 2;
    float4 v = *reinterpret_cast<const float4*>(wih + (size_t)j * 2560 + k);
    f16x4 o = { (_Float16)v.x, (_Float16)v.y, (_Float16)v.z, (_Float16)v.w };
    *reinterpret_cast<f16x4*>(w1 + ((size_t)j << 11) + k) = o;
}

// ---------- convert W_hh and W_ih[:, 2048:2560] -> f16 [j][k 0..512) ----------
__global__ __launch_bounds__(256) void conv_wc(const float* __restrict__ whh,
                                               const float* __restrict__ wih,
                                               f16* __restrict__ whhf,
                                               f16* __restrict__ w2f) {
    int gid = blockIdx.x * 256 + threadIdx.x;
    int j = gid >> 7;
    int k = (gid & 127) << 2;
    float4 a = *reinterpret_cast<const float4*>(whh + (size_t)j * 512 + k);
    f16x4 oa = { (_Float16)a.x, (_Float16)a.y, (_Float16)a.z, (_Float16)a.w };
    *reinterpret_cast<f16x4*>(whhf + ((size_t)j << 9) + k) = oa;
    float4 bv = *reinterpret_cast<const float4*>(wih + (size_t)j * 2560 + 2048 + k);
    f16x4 ob = { (_Float16)bv.x, (_Float16)bv.y, (_Float16)bv.z, (_Float16)bv.w };
    *reinterpret_cast<f16x4*>(w2f + ((size_t)j << 9) + k) = ob;
}

// ---------- G = XC @ W1^T + (b_ih+b_hh), f16 MFMA, fp32 out ----------
__global__ __launch_bounds__(256) void gemm_pre(const f16* __restrict__ XC,
                                                const f16* __restrict__ W1,
                                                const float* __restrict__ b_ih,
                                                const float* __restrict__ b_hh,
                                                float* __restrict__ G) {
    int w = threadIdx.x >> 6, l = threadIdx.x & 63;
    int R0 = blockIdx.y * 128 + (w >> 1) * 64;
    int C0 = blockIdx.x * 128 + (w & 1) * 64;
    int lr = l & 15, kb = l >> 4;
    f32x4 acc[4][4] = {};
    const f16* Abase = XC + (size_t)(R0 + lr) * 2048 + kb * 8;
    const f16* Bbase = W1 + (size_t)(C0 + lr) * 2048 + kb * 8;
    for (int kk = 0; kk < 2048; kk += 32) {
        f16x8 av[4], bv[4];
#pragma unroll
        for (int i = 0; i < 4; i++)
            av[i] = *reinterpret_cast<const f16x8*>(Abase + (size_t)(i * 16) * 2048 + kk);
#pragma unroll
        for (int i = 0; i < 4; i++)
            bv[i] = *reinterpret_cast<const f16x8*>(Bbase + (size_t)(i * 16) * 2048 + kk);
#pragma unroll
        for (int fr = 0; fr < 4; fr++)
#pragma unroll
            for (int fc = 0; fc < 4; fc++)
                acc[fr][fc] = __builtin_amdgcn_mfma_f32_16x16x32_f16(av[fr], bv[fc], acc[fr][fc], 0, 0, 0);
    }
#pragma unroll
    for (int fc = 0; fc < 4; fc++) {
        int col = C0 + fc * 16 + lr;
        float bias = b_ih[col] + b_hh[col];
#pragma unroll
        for (int fr = 0; fr < 4; fr++) {
#pragma unroll
            for (int r = 0; r < 4; r++) {
                int row = R0 + fr * 16 + kb * 4 + r;
                G[(size_t)row * 2048 + col] = acc[fr][fc][r] + bias;
            }
        }
    }
}

// ---------- sequential chain: 32 persistent WGs x 512 threads ----------
// wave wv = tid>>6; gate w = wv&3; m = wv>>2 (0=Whh critical+poll, 1=W2 slack).
// lane: u=l&15 (hidden unit of this WG's 16), q=l>>4 (k-quarter, 128 f16).
// Per-thread weights: 128 f16 = 64 f16x2 VGPRs, register-resident.
__global__ __launch_bounds__(512, 1) void lstm_chain(const float* __restrict__ G,
                                                     const f16* __restrict__ Whhf,
                                                     const f16* __restrict__ W2f,
                                                     f16* __restrict__ h_ring,
                                                     int* __restrict__ flags,
                                                     float* __restrict__ out) {
    const int wg = blockIdx.x;
    const int tid = threadIdx.x;
    const int wv = tid >> 6;
    const int w = wv & 3;
    const int m = wv >> 2;
    const int l = tid & 63;
    const int u = l & 15;
    const int q = l >> 4;
    const int row = w * 512 + wg * 16 + u;

    const f16* Wsrc = (m ? W2f : Whhf) + (size_t)row * 512 + q * 128;
    f16x2 wr[64];
#pragma unroll
    for (int i = 0; i < 16; i++) {
        f16x8 v = reinterpret_cast<const f16x8*>(Wsrc)[i];
        wr[4 * i + 0] = v.lo.lo;
        wr[4 * i + 1] = v.lo.hi;
        wr[4 * i + 2] = v.hi.lo;
        wr[4 * i + 3] = v.hi.hi;
    }

    __shared__ float part[2][2][4][16];   // [buf][m][gate][unit]
    float cstate = 0.0f;
    const ull* ring64 = (const ull*)h_ring;

    for (int t = 0; t < T_TOT; t++) {
        const int buf = t & 1;
        float gval = 0.0f;
        if (m == 0 && l < 16)
            gval = G[(size_t)t * 2048 + row];    // row == w*512+wg*16+l here

        float a0 = 0.f, a1 = 0.f, a2 = 0.f, a3 = 0.f;

        if (m == 1) {
            // W2 . h[t-64] : 64 steps of slack, no poll needed (bounded by syncthreads skew)
            if (t >= 64) {
                const ull* hp = ring64 + (size_t)((t - 64) & (RING - 1)) * 128 + q * 32;
#pragma unroll
                for (int i = 0; i < 32; i += 4) {
                    ull v0 = ld_a64(hp + i + 0);
                    ull v1 = ld_a64(hp + i + 1);
                    ull v2 = ld_a64(hp + i + 2);
                    ull v3 = ld_a64(hp + i + 3);
                    f16x4 h0 = __builtin_bit_cast(f16x4, v0);
                    f16x4 h1 = __builtin_bit_cast(f16x4, v1);
                    f16x4 h2 = __builtin_bit_cast(f16x4, v2);
                    f16x4 h3 = __builtin_bit_cast(f16x4, v3);
                    a0 = dot2f(wr[2 * i + 0], h0.lo, a0);
                    a0 = dot2f(wr[2 * i + 1], h0.hi, a0);
                    a1 = dot2f(wr[2 * i + 2], h1.lo, a1);
                    a1 = dot2f(wr[2 * i + 3], h1.hi, a1);
                    a2 = dot2f(wr[2 * i + 4], h2.lo, a2);
                    a2 = dot2f(wr[2 * i + 5], h2.hi, a2);
                    a3 = dot2f(wr[2 * i + 6], h3.lo, a3);
                    a3 = dot2f(wr[2 * i + 7], h3.hi, a3);
                }
            }
        } else {
            // wait until every WG finished step t-1 (relaxed polls, no cache fences)
            if (t > 0) {
                while (true) {
                    int f = 0x7fffffff;
                    if (l < NWG) f = ld_a32(flags + l);
                    if (__all(f >= t)) break;
                }
            }
            // W_hh . h[t-1] — the critical dot
            const ull* hp = ring64 + (size_t)((t - 1) & (RING - 1)) * 128 + q * 32;
#pragma unroll
            for (int i = 0; i < 32; i += 4) {
                ull v0 = ld_a64(hp + i + 0);
                ull v1 = ld_a64(hp + i + 1);
                ull v2 = ld_a64(hp + i + 2);
                ull v3 = ld_a64(hp + i + 3);
                f16x4 h0 = __builtin_bit_cast(f16x4, v0);
                f16x4 h1 = __builtin_bit_cast(f16x4, v1);
                f16x4 h2 = __builtin_bit_cast(f16x4, v2);
                f16x4 h3 = __builtin_bit_cast(f16x4, v3);
                a0 = dot2f(wr[2 * i + 0], h0.lo, a0);
                a0 = dot2f(wr[2 * i + 1], h0.hi, a0);
                a1 = dot2f(wr[2 * i + 2], h1.lo, a1);
                a1 = dot2f(wr[2 * i + 3], h1.hi, a1);
                a2 = dot2f(wr[2 * i + 4], h2.lo, a2);
                a2 = dot2f(wr[2 * i + 5], h2.hi, a2);
                a3 = dot2f(wr[2 * i + 6], h3.lo, a3);
                a3 = dot2f(wr[2 * i + 7], h3.hi, a3);
            }
        }
        float acc = (a0 + a1) + (a2 + a3);
        acc += __shfl_xor(acc, 16);
        acc += __shfl_xor(acc, 32);
        if (l < 16) part[buf][m][w][l] = acc + gval;
        __syncthreads();

        if (tid < 16) {
            float gi = part[buf][0][0][tid] + part[buf][1][0][tid];
            float gf = part[buf][0][1][tid] + part[buf][1][1][tid];
            float gg = part[buf][0][2][tid] + part[buf][1][2][tid];
            float go = part[buf][0][3][tid] + part[buf][1][3][tid];
            cstate = sigf(gf) * cstate + sigf(gi) * tanhfast(gg);
            float hval = sigf(go) * tanhfast(cstate);
            int b = t & 63, s = t >> 6;
            out[((size_t)(b << 8) + s) * 512 + wg * 16 + tid] = hval;
            // pack 16 f16 into 4x 8B and push to L3
            f16x4 hp4;
            hp4[0] = (f16)__shfl(hval, 4 * tid + 0);
            hp4[1] = (f16)__shfl(hval, 4 * tid + 1);
            hp4[2] = (f16)__shfl(hval, 4 * tid + 2);
            hp4[3] = (f16)__shfl(hval, 4 * tid + 3);
            if (tid < 4) {
                ull* dst = (ull*)h_ring + ((size_t)(t & (RING - 1)) * 128 + wg * 4 + tid);
                st_a64(dst, __builtin_bit_cast(ull, hp4));
            }
            // h stores must land at L3 before the flag is raised
            asm volatile("s_waitcnt vmcnt(0)" ::: "memory");
            if (tid == 0) st_a32(flags + wg, t + 1);
        }
    }
}

extern "C" void kernel_launch(void* const* d_in, const int* in_sizes, int n_in,
                              void* d_out, int out_size, void* d_ws, size_t ws_size,
                              hipStream_t stream) {
    const float* x    = (const float*)d_in[0];
    const float* hi   = (const float*)d_in[1];
    const float* W_ih = (const float*)d_in[2];
    const float* W_hh = (const float*)d_in[3];
    const float* b_ih = (const float*)d_in[4];
    const float* b_hh = (const float*)d_in[5];

    char* ws = (char*)d_ws;
    f16*   XCf   = (f16*)(ws + O_XC);
    f16*   W1f   = (f16*)(ws + O_W1);
    f16*   Whhf  = (f16*)(ws + O_WHH);
    f16*   W2f   = (f16*)(ws + O_W2);
    float* G     = (float*)(ws + O_G);
    f16*   hring = (f16*)(ws + O_RING);
    int*   flags = (int*)(ws + O_FLAGS);

    // zero h_ring (slot 127 = h[-1]=0) + flags every launch
    hipMemsetAsync(hring, 0, (RING * HD * sizeof(f16)) + 128, stream);

    conv_xc<<<32768, 256, 0, stream>>>(x, hi, XCf);
    conv_w1<<<4096, 256, 0, stream>>>(W_ih, W1f);
    conv_wc<<<1024, 256, 0, stream>>>(W_hh, W_ih, Whhf, W2f);
    gemm_pre<<<dim3(16, 128), 256, 0, stream>>>(XCf, W1f, b_ih, b_hh, G);
    lstm_chain<<<NWG, 512, 0, stream>>>(G, Whhf, W2f, hring, flags, (float*)d_out);
}